// Round 1
// baseline (61.681 us; speedup 1.0000x reference)
//
#include <hip/hip_runtime.h>

// QConv1D quantum-circuit conv, analytically reduced.
//
// Per (oc, patch): exp_val = <chi| CZ (⊗_q a_q Z + b_q X) CZ |chi>,
// chi = product state with Bloch r_q = (cos x_q cos t1, sin x_q, -cos x_q sin t1),
// a = cos t2, b = -sin t2  (t1 = weight[oc][q][0], t2 = weight[oc][q][1]).
// Expanding over subsets S of the 6-ring (CZ conjugation adds Z's on neighbors):
//   exp_val = sum_{s=0..63} T[oc][s] * prod_q u_q(s),
// u_q in {1, cos x_q, sin x_q} determined ONLY by ring structure of s:
//   q in S,  n_q odd  -> sin x_q   (coeff factor b, one i each; n1 even overall)
//   q in S,  n_q even -> cos x_q   (coeff factor b*c1)
//   q out S, n_q even -> cos x_q   (coeff factor -a*s1, from rz)
//   q out S, n_q odd  -> 1         (coeff factor a)
// with sign (-1)^{E_SS} * (-1)^{n1/2};  n_q = #ring-neighbors of q in S.
//
// Output scramble (reference reshape quirk, Bn==OUT_CH==16, L_out*OUT_CH==Np):
//   out[oc*16352 + (p%16)*1022 + p/16] = exp_val(oc, p),  p = b*1022 + l.

#define L_IN  1024
#define L_OUT 1022
#define NP    16352   // 16 * 1022
#define NS    64

__global__ __launch_bounds__(256) void qconv_kernel(
    const float* __restrict__ x, const float* __restrict__ w,
    float* __restrict__ out)
{
    __shared__ float wtrig[16][6][4];   // c1, s1, c2, s2 per (oc, q)
    __shared__ float T[NS * 16];        // T[s*16 + oc]

    const int tid = threadIdx.x;

    // ---- stage weight trig (full angles) ----
    if (tid < 96) {
        const int oc = tid / 6, q = tid - oc * 6;
        const float th1 = w[(oc * 6 + q) * 2 + 0];
        const float th2 = w[(oc * 6 + q) * 2 + 1];
        float s1, c1, s2, c2;
        __sincosf(th1, &s1, &c1);
        __sincosf(th2, &s2, &c2);
        wtrig[oc][q][0] = c1; wtrig[oc][q][1] = s1;
        wtrig[oc][q][2] = c2; wtrig[oc][q][3] = s2;
    }
    __syncthreads();

    // ---- build coefficient table T[s][oc] (redundant per block; tiny) ----
    for (int i = tid; i < NS * 16; i += 256) {
        const int s = i >> 4, oc = i & 15;
        float prod = 1.f;
        int ess = 0, n1 = 0;
        #pragma unroll
        for (int q = 0; q < 6; ++q) {
            const int in  = (s >> q) & 1;
            const int nxt = (s >> ((q + 1) % 6)) & 1;
            const int prv = (s >> ((q + 5) % 6)) & 1;
            const int odd = (nxt + prv) & 1;
            const float c1 = wtrig[oc][q][0], s1 = wtrig[oc][q][1];
            const float c2 = wtrig[oc][q][2], s2 = wtrig[oc][q][3];
            const float f = in ? (odd ? -s2 : -s2 * c1)
                               : (odd ?  c2 : -c2 * s1);
            ess += in & nxt;
            n1  += in & odd;
            prod *= f;
        }
        if ((ess ^ (n1 >> 1)) & 1) prod = -prod;
        T[i] = prod;
    }
    __syncthreads();

    // ---- main: one thread = (patch, oc) ----
    const int oc = tid & 15;
    const int p  = blockIdx.x * 16 + (tid >> 4);
    const int bi = p / L_OUT;
    const int li = p - bi * L_OUT;

    const float* xb = x + bi * (2 * L_IN) + li;
    float cx[6], sx[6];
    #pragma unroll
    for (int c = 0; c < 2; ++c) {
        #pragma unroll
        for (int k = 0; k < 3; ++k) {
            const float v = xb[c * L_IN + k];     // qubit q = c*3 + k
            __sincosf(v, &sx[c * 3 + k], &cx[c * 3 + k]);
        }
    }

    float acc = 0.f;
    #pragma unroll
    for (int s = 0; s < NS; ++s) {
        float m = T[(s << 4) | oc];
        #pragma unroll
        for (int q = 0; q < 6; ++q) {
            const int in  = (s >> q) & 1;
            const int odd = (((s >> ((q + 1) % 6)) & 1) +
                             ((s >> ((q + 5) % 6)) & 1)) & 1;
            if (in)        m *= odd ? sx[q] : cx[q];
            else if (!odd) m *= cx[q];
        }
        acc += m;
    }

    // scrambled output layout (see header comment)
    out[oc * NP + (p & 15) * L_OUT + (p >> 4)] = acc;
}

extern "C" void kernel_launch(void* const* d_in, const int* in_sizes, int n_in,
                              void* d_out, int out_size, void* d_ws, size_t ws_size,
                              hipStream_t stream) {
    const float* x = (const float*)d_in[0];   // (16, 2, 1024) fp32
    const float* w = (const float*)d_in[1];   // (16, 6, 2)    fp32
    float* out = (float*)d_out;               // (16, 16, 1022) fp32
    qconv_kernel<<<dim3(NP / 16), dim3(256), 0, stream>>>(x, w, out);
}

// Round 2
// 61.012 us; speedup vs baseline: 1.0110x; 1.0110x over previous
//
#include <hip/hip_runtime.h>

// QConv1D quantum-circuit conv, analytically reduced to 64 monomials.
//
// exp_val(oc,p) = sum_{s=0..63} T[oc][s] * M_p[s],
//   M_p[s] = prod_q u_q(s),  u_q = odd ? (in ? sin x_q : 1) : cos x_q
//   (in = q in S; odd = parity of ring-neighbors of q in S)
// T[oc][s] = sign * prod_q f_q,  f = in ? (odd ? -s2 : -s2*c1)
//                                       : (odd ?  c2 : -c2*s1),
//   sign = (-1)^{E_SS} * (-1)^{n1/2}   (validated in R1, absmax 2e-3).
//
// R2: one thread = (patch, 8-oc half). Removes the 16x redundant sincos +
// monomial computation of R1 (~4x fewer lane-instrs). T reads are 2x
// ds_read_b128 per s, 2 distinct addrs/wave -> broadcast, conflict-free.
//
// Output scramble (reference reshape quirk, Bn==OUT_CH==16, L_out*OUT_CH==Np):
//   out[oc*16352 + (p%16)*1022 + p/16] = exp_val(oc, p).

#define L_IN  1024
#define L_OUT 1022
#define NP    16352   // 16 * 1022
#define NS    64

__global__ __launch_bounds__(256) void qconv_kernel(
    const float* __restrict__ x, const float* __restrict__ w,
    float* __restrict__ out)
{
    __shared__ float wtrig[16][6][4];   // c1, s1, c2, s2 per (oc, q)
    __shared__ float T[NS * 16];        // T[s*16 + oc]

    const int tid = threadIdx.x;

    // ---- stage weight trig (full angles) ----
    if (tid < 96) {
        const int oc = tid / 6, q = tid - oc * 6;
        const float th1 = w[(oc * 6 + q) * 2 + 0];
        const float th2 = w[(oc * 6 + q) * 2 + 1];
        float s1, c1, s2, c2;
        __sincosf(th1, &s1, &c1);
        __sincosf(th2, &s2, &c2);
        wtrig[oc][q][0] = c1; wtrig[oc][q][1] = s1;
        wtrig[oc][q][2] = c2; wtrig[oc][q][3] = s2;
    }
    __syncthreads();

    // ---- build coefficient table T[s][oc] (redundant per block; tiny) ----
    for (int i = tid; i < NS * 16; i += 256) {
        const int s = i >> 4, oc = i & 15;
        float prod = 1.f;
        int ess = 0, n1 = 0;
        #pragma unroll
        for (int q = 0; q < 6; ++q) {
            const int in  = (s >> q) & 1;
            const int nxt = (s >> ((q + 1) % 6)) & 1;
            const int prv = (s >> ((q + 5) % 6)) & 1;
            const int odd = (nxt + prv) & 1;
            const float c1 = wtrig[oc][q][0], s1 = wtrig[oc][q][1];
            const float c2 = wtrig[oc][q][2], s2 = wtrig[oc][q][3];
            const float f = in ? (odd ? -s2 : -s2 * c1)
                               : (odd ?  c2 : -c2 * s1);
            ess += in & nxt;
            n1  += in & odd;
            prod *= f;
        }
        if ((ess ^ (n1 >> 1)) & 1) prod = -prod;
        T[i] = prod;
    }
    __syncthreads();

    // ---- main: one thread = (patch, 8-oc half) ----
    const int gid  = blockIdx.x * 256 + tid;
    const int p    = gid >> 1;
    const int half = gid & 1;
    if (p >= NP) return;

    const int bi = p / L_OUT;
    const int li = p - bi * L_OUT;

    const float* xb = x + bi * (2 * L_IN) + li;
    float cx[6], sx[6];
    #pragma unroll
    for (int c = 0; c < 2; ++c) {
        #pragma unroll
        for (int k = 0; k < 3; ++k) {
            const float v = xb[c * L_IN + k];     // qubit q = c*3 + k
            __sincosf(v, &sx[c * 3 + k], &cx[c * 3 + k]);
        }
    }

    float acc[8];
    #pragma unroll
    for (int j = 0; j < 8; ++j) acc[j] = 0.f;

    const float* Tb = T + half * 8;
    #pragma unroll
    for (int s = 0; s < NS; ++s) {
        // monomial M[s]; straight-line, compiler CSEs shared subproducts
        float m = 1.f;
        #pragma unroll
        for (int q = 0; q < 6; ++q) {
            const int in  = (s >> q) & 1;
            const int odd = (((s >> ((q + 1) % 6)) ^ (s >> ((q + 5) % 6)))) & 1;
            if (odd) { if (in) m *= sx[q]; }
            else       m *= cx[q];
        }
        #pragma unroll
        for (int j = 0; j < 8; ++j)
            acc[j] = fmaf(Tb[s * 16 + j], m, acc[j]);
    }

    // scrambled output layout (see header comment)
    const int obase = (p & 15) * L_OUT + (p >> 4);
    #pragma unroll
    for (int j = 0; j < 8; ++j)
        out[(half * 8 + j) * NP + obase] = acc[j];
}

extern "C" void kernel_launch(void* const* d_in, const int* in_sizes, int n_in,
                              void* d_out, int out_size, void* d_ws, size_t ws_size,
                              hipStream_t stream) {
    const float* x = (const float*)d_in[0];   // (16, 2, 1024) fp32
    const float* w = (const float*)d_in[1];   // (16, 6, 2)    fp32
    float* out = (float*)d_out;               // (16, 16, 1022) fp32
    qconv_kernel<<<dim3((2 * NP + 255) / 256), dim3(256), 0, stream>>>(x, w, out);
}